// Round 21
// baseline (677.197 us; speedup 1.0000x reference)
//
#include <hip/hip_runtime.h>
#include <hip/hip_cooperative_groups.h>

namespace cg = cooperative_groups;

// GraphSAGE 4×SAGEConv + MLP head, fp32 in/out.
// R21: R20's cooperative mega-kernel never launched (return code discarded).
// Hardened: (a) check hipLaunchCooperativeKernel; on failure run the proven
// R19 5-kernel path (worst case = 150.5us, passing). (b) coop path: plain
// stores for binned0, __threadfence() before each grid.sync(), all blocks
// reach all syncs.

#define SH      8
#define BWID    256
#define NBK     512
#define CHUNK   4096
#define EPTC    (CHUNK / 512)   // mega: 8 edges/thread @512
#define EPTB    (CHUNK / 256)   // fallback bin: 16 edges/thread @256
#define BCAP    5120

__device__ __forceinline__ float silu_f(float v) {
    return v * __builtin_amdgcn_rcpf(1.0f + __expf(-v));
}
__device__ __forceinline__ float bf_lo(unsigned u) { return __uint_as_float(u << 16); }
__device__ __forceinline__ float bf_hi(unsigned u) { return __uint_as_float(u & 0xFFFF0000u); }
__device__ __forceinline__ unsigned short f2bf(float f) {
    unsigned x = __float_as_uint(f);
    unsigned r = x + 0x7FFFu + ((x >> 16) & 1u);
    return (unsigned short)(r >> 16);
}
__device__ __forceinline__ unsigned pack_bf2(float a, float b) {
    return (unsigned)f2bf(a) | ((unsigned)f2bf(b) << 16);
}
__device__ __forceinline__ int wave_iscan(int v, int lane) {
#pragma unroll
    for (int d = 1; d < 64; d <<= 1) {
        const int tv = __shfl_up(v, d);
        if (lane >= d) v += tv;
    }
    return v;
}

#define ACC2(u0, u1) \
    p[0] += bf_lo(u0.x); p[1] += bf_hi(u0.x); p[2] += bf_lo(u0.y); p[3] += bf_hi(u0.y); \
    p[4] += bf_lo(u0.z); p[5] += bf_hi(u0.z); p[6] += bf_lo(u0.w); p[7] += bf_hi(u0.w); \
    p[8] += bf_lo(u1.x); p[9] += bf_hi(u1.x); p[10]+= bf_lo(u1.y); p[11]+= bf_hi(u1.y); \
    p[12]+= bf_lo(u1.z); p[13]+= bf_hi(u1.z); p[14]+= bf_lo(u1.w); p[15]+= bf_hi(u1.w);

__device__ __forceinline__ void gather16_2(
    const int* __restrict__ binned1, const uint4* __restrict__ h4,
    int beg, int end, int q, float* p)
{
#pragma unroll
    for (int i = 0; i < 16; ++i) p[i] = 0.f;
    int base = beg;
    for (; base + 8 <= end; base += 8) {
        const int k = base + q * 4;
        const int i0 = binned1[k],     i1 = binned1[k + 1];
        const int i2 = binned1[k + 2], i3 = binned1[k + 3];
        const uint4 a0 = h4[(size_t)i0 * 2], a1 = h4[(size_t)i0 * 2 + 1];
        const uint4 b0 = h4[(size_t)i1 * 2], b1 = h4[(size_t)i1 * 2 + 1];
        const uint4 c0 = h4[(size_t)i2 * 2], c1 = h4[(size_t)i2 * 2 + 1];
        const uint4 d0 = h4[(size_t)i3 * 2], d1 = h4[(size_t)i3 * 2 + 1];
        ACC2(a0, a1) ACC2(b0, b1) ACC2(c0, c1) ACC2(d0, d1)
    }
    for (int k = base + q; k < end; k += 2) {
        const int s0 = binned1[k];
        const uint4 a0 = h4[(size_t)s0 * 2], a1 = h4[(size_t)s0 * 2 + 1];
        ACC2(a0, a1)
    }
#pragma unroll
    for (int i = 0; i < 16; ++i) p[i] += __shfl_xor(p[i], 1);
}

__device__ __forceinline__ void gather16_4(
    const int* __restrict__ binned1, const uint4* __restrict__ h4,
    int beg, int end, int q, float* p)
{
#pragma unroll
    for (int i = 0; i < 16; ++i) p[i] = 0.f;
    int base = beg;
    for (; base + 16 <= end; base += 16) {
        const int k = base + q * 4;
        const int i0 = binned1[k],     i1 = binned1[k + 1];
        const int i2 = binned1[k + 2], i3 = binned1[k + 3];
        const uint4 a0 = h4[(size_t)i0 * 2], a1 = h4[(size_t)i0 * 2 + 1];
        const uint4 b0 = h4[(size_t)i1 * 2], b1 = h4[(size_t)i1 * 2 + 1];
        const uint4 c0 = h4[(size_t)i2 * 2], c1 = h4[(size_t)i2 * 2 + 1];
        const uint4 d0 = h4[(size_t)i3 * 2], d1 = h4[(size_t)i3 * 2 + 1];
        ACC2(a0, a1) ACC2(b0, b1) ACC2(c0, c1) ACC2(d0, d1)
    }
    for (int k = base + q; k < end; k += 4) {
        const int s0 = binned1[k];
        const uint4 a0 = h4[(size_t)s0 * 2], a1 = h4[(size_t)s0 * 2 + 1];
        ACC2(a0, a1)
    }
#pragma unroll
    for (int i = 0; i < 16; ++i) p[i] += __shfl_xor(p[i], 1);
#pragma unroll
    for (int i = 0; i < 16; ++i) p[i] += __shfl_xor(p[i], 2);
}

// shared agg+dense body (2-lane): gather -> silu -> dual 16x16 dense
__device__ __forceinline__ void agg_dense_body(
    const int* __restrict__ binned1, const unsigned* __restrict__ hl_in,
    const float* __restrict__ acc_in, const float* sW,
    unsigned* __restrict__ hl_out, float* __restrict__ acc_out,
    int node, int q, int beg, int end)
{
    float p[16];
    gather16_2(binned1, (const uint4*)hl_in, beg, end, q, p);

    const float4* __restrict__ ai = (const float4*)(acc_in + (size_t)node * 16);
    float h[16];
#pragma unroll
    for (int r = 0; r < 4; ++r) {
        const float4 a = ai[r];
        h[4*r+0] = silu_f(a.x + p[4*r+0]);
        h[4*r+1] = silu_f(a.y + p[4*r+1]);
        h[4*r+2] = silu_f(a.z + p[4*r+2]);
        h[4*r+3] = silu_f(a.w + p[4*r+3]);
    }

    const float4* sWl4 = (const float4*)sW;
    const float4* sWr4 = (const float4*)(sW + 256);
    const float*  sbl  = sW + 512;
    float ol[8], oa[8];
#pragma unroll
    for (int jj = 0; jj < 8; ++jj) {
        const int j = 8 * q + jj;
        float al = 0.f, ar = 0.f;
#pragma unroll
        for (int d4 = 0; d4 < 4; ++d4) {
            const float4 wl = sWl4[j * 4 + d4];
            const float4 wr = sWr4[j * 4 + d4];
            al = fmaf(wl.x, h[4*d4+0], al); al = fmaf(wl.y, h[4*d4+1], al);
            al = fmaf(wl.z, h[4*d4+2], al); al = fmaf(wl.w, h[4*d4+3], al);
            ar = fmaf(wr.x, h[4*d4+0], ar); ar = fmaf(wr.y, h[4*d4+1], ar);
            ar = fmaf(wr.z, h[4*d4+2], ar); ar = fmaf(wr.w, h[4*d4+3], ar);
        }
        ol[jj] = al;
        oa[jj] = sbl[j] + ar;
    }

    ((uint4*)hl_out)[(size_t)node * 2 + q] =
        make_uint4(pack_bf2(ol[0], ol[1]), pack_bf2(ol[2], ol[3]),
                   pack_bf2(ol[4], ol[5]), pack_bf2(ol[6], ol[7]));
    float4* __restrict__ ap = (float4*)(acc_out + (size_t)node * 16);
    ap[2 * q]     = make_float4(oa[0], oa[1], oa[2], oa[3]);
    ap[2 * q + 1] = make_float4(oa[4], oa[5], oa[6], oa[7]);
}

// ================= cooperative mega-kernel =================
__global__ __launch_bounds__(512, 4) void mega(
    const int* __restrict__ src, const int* __restrict__ dst,
    const float* __restrict__ x,
    const float* __restrict__ Wl0, const float* __restrict__ bl0,
    const float* __restrict__ Wr0,
    const float* __restrict__ Wls, const float* __restrict__ bls,
    const float* __restrict__ Wrs,
    const float* __restrict__ W1, const float* __restrict__ b1,
    const float* __restrict__ W2, const float* __restrict__ b2,
    const float* __restrict__ W3, const float* __restrict__ b3,
    float* __restrict__ out,
    unsigned short* __restrict__ cnt16, unsigned short* __restrict__ scan16,
    unsigned* __restrict__ binned0, int* __restrict__ binned1,
    unsigned* __restrict__ hlbA, unsigned* __restrict__ hlbB,
    float* __restrict__ acc0, float* __restrict__ acc1,
    int n, int ne, int nblocks, int nbuck)
{
    cg::grid_group grid = cg::this_grid();

    __shared__ unsigned s_buf[BCAP];
    __shared__ int      s_hist[512];
    __shared__ int      s_off[512];
    __shared__ int      s_ws[8];
    __shared__ float    sW[1040];

    const int t = threadIdx.x;
    const int lane = t & 63, w = t >> 6;
    const int blk = blockIdx.x;

    // ---- Phase A: bin + dense0 ----
    {
        for (int i = t; i < 512; i += 512) { sW[i] = Wl0[i]; sW[512 + i] = Wr0[i]; }
        if (t < 16) sW[1024 + t] = bl0[t];

        const int base = blk * CHUNK;
        const int cnt = (blk < nblocks) ? min(CHUNK, ne - base) : 0;

        int es[EPTC], ed[EPTC];
#pragma unroll
        for (int j = 0; j < EPTC; ++j) {
            const int i = t + j * 512;
            if (i < cnt) {
                es[j] = __builtin_nontemporal_load(src + base + i);
                ed[j] = __builtin_nontemporal_load(dst + base + i);
            } else { es[j] = -1; ed[j] = -1; }
        }

        s_hist[t] = 0;
        __syncthreads();
#pragma unroll
        for (int j = 0; j < EPTC; ++j)
            if (es[j] >= 0) atomicAdd(&s_hist[ed[j] >> SH], 1);
        __syncthreads();

        const int c = s_hist[t];
        const int inc = wave_iscan(c, lane);
        if (lane == 63) s_ws[w] = inc;
        __syncthreads();
        int wbase = 0;
        for (int i = 0; i < w; ++i) wbase += s_ws[i];
        const int ex = inc + wbase - c;
        s_off[t] = ex;
        if (blk < nblocks) {
            cnt16[blk * NBK + t]  = (unsigned short)c;
            scan16[blk * NBK + t] = (unsigned short)ex;
        }
        s_hist[t] = 0;
        __syncthreads();

#pragma unroll
        for (int j = 0; j < EPTC; ++j) {
            if (es[j] >= 0) {
                const int b  = ed[j] >> SH;
                const int ld = ed[j] & (BWID - 1);
                const int r  = atomicAdd(&s_hist[b], 1);
                s_buf[s_off[b] + r] = ((unsigned)ld << 17) | (unsigned)es[j];
            }
        }
        __syncthreads();

        for (int i = t; i < cnt; i += 512)
            binned0[base + i] = s_buf[i];

        if (t < 256) {
            const int node = blk * 256 + t;
            if (node < n) {
                float h[32];
                const float4* xp = (const float4*)(x + (size_t)node * 32);
#pragma unroll
                for (int r = 0; r < 8; ++r) {
                    const float4 vv = xp[r];
                    h[4*r+0] = vv.x; h[4*r+1] = vv.y;
                    h[4*r+2] = vv.z; h[4*r+3] = vv.w;
                }
                const float4* sWl4 = (const float4*)sW;
                const float4* sWr4 = (const float4*)(sW + 512);
                float ol[16], oa[16];
#pragma unroll
                for (int j = 0; j < 16; ++j) {
                    float al = 0.f, ar = 0.f;
#pragma unroll
                    for (int d4 = 0; d4 < 8; ++d4) {
                        const float4 wl = sWl4[j * 8 + d4];
                        const float4 wr = sWr4[j * 8 + d4];
                        al = fmaf(wl.x, h[4*d4+0], al); al = fmaf(wl.y, h[4*d4+1], al);
                        al = fmaf(wl.z, h[4*d4+2], al); al = fmaf(wl.w, h[4*d4+3], al);
                        ar = fmaf(wr.x, h[4*d4+0], ar); ar = fmaf(wr.y, h[4*d4+1], ar);
                        ar = fmaf(wr.z, h[4*d4+2], ar); ar = fmaf(wr.w, h[4*d4+3], ar);
                    }
                    ol[j] = al;
                    oa[j] = sW[1024 + j] + ar;
                }
                unsigned u[8];
#pragma unroll
                for (int r = 0; r < 8; ++r) u[r] = pack_bf2(ol[2*r], ol[2*r+1]);
                uint4* hp = (uint4*)(hlbA + (size_t)node * 8);
                hp[0] = make_uint4(u[0], u[1], u[2], u[3]);
                hp[1] = make_uint4(u[4], u[5], u[6], u[7]);
                float4* ap = (float4*)(acc0 + (size_t)node * 16);
#pragma unroll
                for (int r = 0; r < 4; ++r)
                    ap[r] = make_float4(oa[4*r], oa[4*r+1], oa[4*r+2], oa[4*r+3]);
            }
        }
    }

    __threadfence();
    grid.sync();

    // ---- Phase B: bucket sort + layer 1 ----
    const int b = blk;
    const bool isb = (b < nbuck);
    const int dbase = b * BCAP;
    int* const cnt = s_hist;
    int* const off_ = s_hist + 256;
    {
        for (int i = t; i < 256; i += 512) { sW[i] = Wls[i]; sW[256 + i] = Wrs[i]; }
        if (t < 16) sW[512 + t] = bls[t];

        int rc = 0, rs = 0;
        if (isb && t < nblocks) { rc = cnt16[t * NBK + b]; rs = scan16[t * NBK + b]; }
        const int inc = wave_iscan(rc, lane);
        if (lane == 63) s_ws[w] = inc;
        if (t < 256) cnt[t] = 0;
        __syncthreads();
        int wbase = 0;
        for (int i = 0; i < w; ++i) wbase += s_ws[i];
        const int o = inc + wbase - rc;
        int tot = 0;
        for (int i = 0; i < 8; ++i) tot += s_ws[i];

        if (rc) {
            const unsigned* run = binned0 + (size_t)t * CHUNK + rs;
            for (int r = 0; r < rc; ++r)
                s_buf[o + r] = run[r];
        }
        __syncthreads();

        for (int k = t; k < tot; k += 512)
            atomicAdd(&cnt[s_buf[k] >> 17], 1);
        __syncthreads();

        const int c = (t < 256) ? cnt[t] : 0;
        const int inc2 = wave_iscan(c, lane);
        if (lane == 63 && w < 4) s_ws[w] = inc2;
        __syncthreads();
        if (t < 256) {
            int wb2 = 0;
            for (int i = 0; i < w; ++i) wb2 += s_ws[i];
            off_[t] = inc2 + wb2 - c;
            cnt[t] = 0;
        }
        __syncthreads();

        for (int k = t; k < tot; k += 512) {
            const unsigned u = s_buf[k];
            const int ld = (int)(u >> 17);
            const int r2 = atomicAdd(&cnt[ld], 1);
            binned1[dbase + off_[ld] + r2] = (int)(u & 0x1FFFFu);
        }
        __syncthreads();

        const int ln = t >> 1;
        const int node = (b << SH) + ln;
        if (isb && node < n)
            agg_dense_body(binned1, hlbA, acc0, sW, hlbB, acc1,
                           node, t & 1, dbase + off_[ln], dbase + off_[ln] + cnt[ln]);
    }

    __threadfence();
    grid.sync();

    // ---- Phase C: layer 2 ----
    {
        for (int i = t; i < 256; i += 512) { sW[i] = Wls[256 + i]; sW[256 + i] = Wrs[256 + i]; }
        if (t < 16) sW[512 + t] = bls[16 + t];
        __syncthreads();
        const int ln = t >> 1;
        const int node = (b << SH) + ln;
        if (isb && node < n)
            agg_dense_body(binned1, hlbB, acc1, sW, hlbA, acc0,
                           node, t & 1, dbase + off_[ln], dbase + off_[ln] + cnt[ln]);
    }

    __threadfence();
    grid.sync();

    // ---- Phase D: layer 3 ----
    {
        for (int i = t; i < 256; i += 512) { sW[i] = Wls[512 + i]; sW[256 + i] = Wrs[512 + i]; }
        if (t < 16) sW[512 + t] = bls[32 + t];
        __syncthreads();
        const int ln = t >> 1;
        const int node = (b << SH) + ln;
        if (isb && node < n)
            agg_dense_body(binned1, hlbA, acc0, sW, hlbB, acc1,
                           node, t & 1, dbase + off_[ln], dbase + off_[ln] + cnt[ln]);
    }

    __threadfence();
    grid.sync();

    // ---- Phase E: layer-4 agg + MLP head ----
    {
        float* sW1f = (float*)s_buf;
        float* sW2f = (float*)s_buf + 512;
        for (int i = t; i < 512; i += 512) sW1f[i] = W1[i];
        for (int i = t; i < 1024; i += 512) sW2f[i] = W2[i];
        if (t < 32) { sW[t] = b1[t]; sW[32 + t] = b2[t]; sW[64 + t] = W3[t]; }
        if (t == 0) sW[96] = b3[0];
        __syncthreads();

        const int ln = t >> 1;
        const int node = (b << SH) + ln;
        if (!isb || node >= n) return;
        const int q = t & 1;
        const int beg = dbase + off_[ln];
        const int end = beg + cnt[ln];

        float p[16];
        gather16_2(binned1, (const uint4*)hlbB, beg, end, q, p);

        const float4* ai = (const float4*)(acc1 + (size_t)node * 16);
        float h[16];
#pragma unroll
        for (int r = 0; r < 4; ++r) {
            const float4 a = ai[r];
            h[4*r+0] = silu_f(a.x + p[4*r+0]);
            h[4*r+1] = silu_f(a.y + p[4*r+1]);
            h[4*r+2] = silu_f(a.z + p[4*r+2]);
            h[4*r+3] = silu_f(a.w + p[4*r+3]);
        }

        const float4* sW1v = (const float4*)sW1f;
        float a1[16];
#pragma unroll
        for (int jj = 0; jj < 16; ++jj) {
            const int j = 16 * q + jj;
            float s = sW[j];
#pragma unroll
            for (int d4 = 0; d4 < 4; ++d4) {
                const float4 wv = sW1v[j * 4 + d4];
                s = fmaf(wv.x, h[4*d4+0], s); s = fmaf(wv.y, h[4*d4+1], s);
                s = fmaf(wv.z, h[4*d4+2], s); s = fmaf(wv.w, h[4*d4+3], s);
            }
            a1[jj] = silu_f(s);
        }

        float A1[32];
#pragma unroll
        for (int i = 0; i < 16; ++i) {
            const float mine  = a1[i];
            const float other = __shfl_xor(mine, 1);
            A1[i]      = q ? other : mine;
            A1[16 + i] = q ? mine  : other;
        }

        const float4* sW2v = (const float4*)sW2f;
        float part = 0.f;
#pragma unroll
        for (int jj = 0; jj < 16; ++jj) {
            const int j = 16 * q + jj;
            float s = sW[32 + j];
#pragma unroll
            for (int d4 = 0; d4 < 8; ++d4) {
                const float4 wv = sW2v[j * 8 + d4];
                s = fmaf(wv.x, A1[4*d4+0], s); s = fmaf(wv.y, A1[4*d4+1], s);
                s = fmaf(wv.z, A1[4*d4+2], s); s = fmaf(wv.w, A1[4*d4+3], s);
            }
            part = fmaf(sW[64 + j], silu_f(s), part);
        }
        part += __shfl_xor(part, 1);
        if (q == 0) out[node] = part + sW[96];
    }
}

// ================= fallback (R19) kernels =================

__global__ __launch_bounds__(256) void bin_dense0(
    const int* __restrict__ src, const int* __restrict__ dst,
    unsigned short* __restrict__ cnt16, unsigned short* __restrict__ scan16,
    unsigned* __restrict__ binned0,
    const float* __restrict__ x,
    const float* __restrict__ Wl0, const float* __restrict__ bl0,
    const float* __restrict__ Wr0,
    unsigned* __restrict__ hlb, float* __restrict__ acc,
    int n, int ne, int nblocks)
{
    __shared__ int      s_hist[NBK];
    __shared__ int      s_off[NBK];
    __shared__ int      s_ws[4];
    __shared__ unsigned s_items[CHUNK];
    __shared__ float    sWl[512], sWr[512], sbl[16];

    const int t = threadIdx.x;
    const int lane = t & 63, w = t >> 6;
    const int blk = blockIdx.x;
    for (int i = t; i < 512; i += 256) { sWl[i] = Wl0[i]; sWr[i] = Wr0[i]; }
    if (t < 16) sbl[t] = bl0[t];

    const int base = blk * CHUNK;
    const int cnt = min(CHUNK, ne - base);

    int es[EPTB], ed[EPTB];
#pragma unroll
    for (int j = 0; j < EPTB; ++j) {
        const int i = t + j * 256;
        if (i < cnt) {
            es[j] = __builtin_nontemporal_load(src + base + i);
            ed[j] = __builtin_nontemporal_load(dst + base + i);
        } else { es[j] = -1; ed[j] = -1; }
    }

    s_hist[t] = 0; s_hist[t + 256] = 0;
    __syncthreads();
#pragma unroll
    for (int j = 0; j < EPTB; ++j)
        if (es[j] >= 0) atomicAdd(&s_hist[ed[j] >> SH], 1);
    __syncthreads();

    const int c0 = s_hist[2 * t], c1 = s_hist[2 * t + 1];
    const int ps = c0 + c1;
    const int inc = wave_iscan(ps, lane);
    if (lane == 63) s_ws[w] = inc;
    __syncthreads();
    int wbase = 0;
    for (int i = 0; i < w; ++i) wbase += s_ws[i];
    const int ex = inc + wbase - ps;
    s_off[2 * t] = ex;
    s_off[2 * t + 1] = ex + c0;

    cnt16[blk * NBK + 2 * t]      = (unsigned short)c0;
    cnt16[blk * NBK + 2 * t + 1]  = (unsigned short)c1;
    scan16[blk * NBK + 2 * t]     = (unsigned short)ex;
    scan16[blk * NBK + 2 * t + 1] = (unsigned short)(ex + c0);
    s_hist[t] = 0; s_hist[t + 256] = 0;
    __syncthreads();

#pragma unroll
    for (int j = 0; j < EPTB; ++j) {
        if (es[j] >= 0) {
            const int b  = ed[j] >> SH;
            const int ld = ed[j] & (BWID - 1);
            const int r  = atomicAdd(&s_hist[b], 1);
            s_items[s_off[b] + r] = ((unsigned)ld << 17) | (unsigned)es[j];
        }
    }
    __syncthreads();

    for (int i = t; i < cnt; i += 256)
        __builtin_nontemporal_store(s_items[i], binned0 + base + i);

    const int node = blk * 256 + t;
    if (node >= n) return;

    float h[32];
    const float4* __restrict__ xp = (const float4*)(x + (size_t)node * 32);
#pragma unroll
    for (int r = 0; r < 8; ++r) {
        const float4 vv = xp[r];
        h[4*r+0] = vv.x; h[4*r+1] = vv.y; h[4*r+2] = vv.z; h[4*r+3] = vv.w;
    }

    const float4* __restrict__ sWl4 = (const float4*)sWl;
    const float4* __restrict__ sWr4 = (const float4*)sWr;
    float ol[16], oa[16];
#pragma unroll
    for (int j = 0; j < 16; ++j) {
        float al = 0.f, ar = 0.f;
#pragma unroll
        for (int d4 = 0; d4 < 8; ++d4) {
            const float4 wl = sWl4[j * 8 + d4];
            const float4 wr = sWr4[j * 8 + d4];
            al = fmaf(wl.x, h[4*d4+0], al); al = fmaf(wl.y, h[4*d4+1], al);
            al = fmaf(wl.z, h[4*d4+2], al); al = fmaf(wl.w, h[4*d4+3], al);
            ar = fmaf(wr.x, h[4*d4+0], ar); ar = fmaf(wr.y, h[4*d4+1], ar);
            ar = fmaf(wr.z, h[4*d4+2], ar); ar = fmaf(wr.w, h[4*d4+3], ar);
        }
        ol[j] = al;
        oa[j] = sbl[j] + ar;
    }

    unsigned u[8];
#pragma unroll
    for (int r = 0; r < 8; ++r) u[r] = pack_bf2(ol[2*r], ol[2*r+1]);
    uint4* __restrict__ hp = (uint4*)(hlb + (size_t)node * 8);
    hp[0] = make_uint4(u[0], u[1], u[2], u[3]);
    hp[1] = make_uint4(u[4], u[5], u[6], u[7]);
    float4* __restrict__ ap = (float4*)(acc + (size_t)node * 16);
#pragma unroll
    for (int r = 0; r < 4; ++r)
        ap[r] = make_float4(oa[4*r], oa[4*r+1], oa[4*r+2], oa[4*r+3]);
}

__global__ __launch_bounds__(512, 4) void sort_agg_dense(
    const unsigned* __restrict__ binned0,
    const unsigned short* __restrict__ cnt16,
    const unsigned short* __restrict__ scan16,
    int* __restrict__ binned1, int2* __restrict__ noff2,
    const unsigned* __restrict__ hl_in, const float* __restrict__ acc_in,
    const float* __restrict__ Wl, const float* __restrict__ bl,
    const float* __restrict__ Wr,
    unsigned* __restrict__ hl_out, float* __restrict__ acc_out,
    int n, int nblocks)
{
    __shared__ unsigned s_edges[BCAP];
    __shared__ int cnt[BWID];
    __shared__ int off_[BWID];
    __shared__ int s_ws[8];
    __shared__ int s_ws2[4];
    __shared__ float sW[528];
    const int b = blockIdx.x, t = threadIdx.x;
    const int lane = t & 63, w = t >> 6;
    const int dbase = b * BCAP;

    if (t < 256) { sW[t] = Wl[t]; sW[256 + t] = Wr[t]; }
    if (t < 16) sW[512 + t] = bl[t];

    int rc = 0, rs = 0;
    if (t < nblocks) { rc = cnt16[t * NBK + b]; rs = scan16[t * NBK + b]; }
    const int inc = wave_iscan(rc, lane);
    if (lane == 63) s_ws[w] = inc;
    if (t < BWID) cnt[t] = 0;
    __syncthreads();
    int wbase = 0;
    for (int i = 0; i < w; ++i) wbase += s_ws[i];
    const int o = inc + wbase - rc;
    int tot = 0;
    for (int i = 0; i < 8; ++i) tot += s_ws[i];

    if (rc) {
        const unsigned* __restrict__ run = binned0 + (size_t)t * CHUNK + rs;
        for (int r = 0; r < rc; ++r)
            s_edges[o + r] = __builtin_nontemporal_load(run + r);
    }
    __syncthreads();

    for (int k = t; k < tot; k += 512)
        atomicAdd(&cnt[s_edges[k] >> 17], 1);
    __syncthreads();

    const int c = (t < BWID) ? cnt[t] : 0;
    const int inc2 = wave_iscan(c, lane);
    if (lane == 63 && w < 4) s_ws2[w] = inc2;
    __syncthreads();
    if (t < BWID) {
        int wb2 = 0;
        for (int i = 0; i < w; ++i) wb2 += s_ws2[i];
        const int e = inc2 + wb2 - c;
        off_[t] = e;
        const int node = (b << SH) + t;
        if (node < n)
            noff2[node] = make_int2(dbase + e, dbase + e + c);
        cnt[t] = 0;
    }
    __syncthreads();

    for (int k = t; k < tot; k += 512) {
        const unsigned u = s_edges[k];
        const int ld = (int)(u >> 17);
        const int r2 = atomicAdd(&cnt[ld], 1);
        binned1[dbase + off_[ld] + r2] = (int)(u & 0x1FFFFu);
    }
    __syncthreads();

    const int ln = t >> 1;
    const int node = (b << SH) + ln;
    if (node >= n) return;
    agg_dense_body(binned1, hl_in, acc_in, sW, hl_out, acc_out,
                   node, t & 1, dbase + off_[ln], dbase + off_[ln] + cnt[ln]);
}

__global__ __launch_bounds__(256, 4) void fused_agg_dense(
    const int2* __restrict__ noff2, const int* __restrict__ binned1,
    const unsigned* __restrict__ hl_in, const float* __restrict__ acc_in,
    const float* __restrict__ Wl, const float* __restrict__ bl,
    const float* __restrict__ Wr,
    unsigned* __restrict__ hl_out, float* __restrict__ acc_out, int n)
{
    __shared__ float sWl[256], sWr[256], sbl[16];
    const int t = threadIdx.x;
    sWl[t] = Wl[t]; sWr[t] = Wr[t];
    if (t < 16) sbl[t] = bl[t];
    __syncthreads();

    const int gid = blockIdx.x * 256 + t;
    const int node = gid >> 2;
    if (node >= n) return;
    const int q = t & 3;
    const int2 be = noff2[node];

    float p[16];
    gather16_4(binned1, (const uint4*)hl_in, be.x, be.y, q, p);

    const float4* __restrict__ ai = (const float4*)(acc_in + (size_t)node * 16);
    float h[16];
#pragma unroll
    for (int r = 0; r < 4; ++r) {
        const float4 a = ai[r];
        h[4*r+0] = silu_f(a.x + p[4*r+0]);
        h[4*r+1] = silu_f(a.y + p[4*r+1]);
        h[4*r+2] = silu_f(a.z + p[4*r+2]);
        h[4*r+3] = silu_f(a.w + p[4*r+3]);
    }

    const float4* __restrict__ sWl4 = (const float4*)sWl;
    const float4* __restrict__ sWr4 = (const float4*)sWr;
    float ol[4], oa[4];
#pragma unroll
    for (int jj = 0; jj < 4; ++jj) {
        const int j = 4 * q + jj;
        float al = 0.f, ar = 0.f;
#pragma unroll
        for (int d4 = 0; d4 < 4; ++d4) {
            const float4 wl = sWl4[j * 4 + d4];
            const float4 wr = sWr4[j * 4 + d4];
            al = fmaf(wl.x, h[4*d4+0], al); al = fmaf(wl.y, h[4*d4+1], al);
            al = fmaf(wl.z, h[4*d4+2], al); al = fmaf(wl.w, h[4*d4+3], al);
            ar = fmaf(wr.x, h[4*d4+0], ar); ar = fmaf(wr.y, h[4*d4+1], ar);
            ar = fmaf(wr.z, h[4*d4+2], ar); ar = fmaf(wr.w, h[4*d4+3], ar);
        }
        ol[jj] = al;
        oa[jj] = sbl[j] + ar;
    }

    ((uint2*)hl_out)[(size_t)node * 4 + q] =
        make_uint2(pack_bf2(ol[0], ol[1]), pack_bf2(ol[2], ol[3]));
    ((float4*)acc_out)[(size_t)node * 4 + q] =
        make_float4(oa[0], oa[1], oa[2], oa[3]);
}

__global__ __launch_bounds__(256, 3) void fused_agg_mlp(
    const int2* __restrict__ noff2, const int* __restrict__ binned1,
    const unsigned* __restrict__ hl_in, const float* __restrict__ acc_in,
    const float* __restrict__ W1, const float* __restrict__ b1,
    const float* __restrict__ W2, const float* __restrict__ b2,
    const float* __restrict__ W3, const float* __restrict__ b3,
    float* __restrict__ out, int n)
{
    __shared__ float sW1[512], sW2[1024], sb1[32], sb2[32], sW3[32];
    __shared__ float sb3;
    const int t = threadIdx.x;
    for (int i = t; i < 512; i += 256) sW1[i] = W1[i];
    for (int i = t; i < 1024; i += 256) sW2[i] = W2[i];
    if (t < 32) { sb1[t] = b1[t]; sb2[t] = b2[t]; sW3[t] = W3[t]; }
    if (t == 0) sb3 = b3[0];
    __syncthreads();

    const int gid = blockIdx.x * 256 + t;
    const int node = gid >> 2;
    if (node >= n) return;
    const int q = t & 3;
    const int2 be = noff2[node];

    float p[16];
    gather16_4(binned1, (const uint4*)hl_in, be.x, be.y, q, p);

    const float4* __restrict__ ai = (const float4*)(acc_in + (size_t)node * 16);
    float h[16];
#pragma unroll
    for (int r = 0; r < 4; ++r) {
        const float4 a = ai[r];
        h[4*r+0] = silu_f(a.x + p[4*r+0]);
        h[4*r+1] = silu_f(a.y + p[4*r+1]);
        h[4*r+2] = silu_f(a.z + p[4*r+2]);
        h[4*r+3] = silu_f(a.w + p[4*r+3]);
    }

    const float4* __restrict__ sW1v = (const float4*)sW1;
    float a1[8];
#pragma unroll
    for (int jj = 0; jj < 8; ++jj) {
        const int j = 8 * q + jj;
        float s = sb1[j];
#pragma unroll
        for (int d4 = 0; d4 < 4; ++d4) {
            const float4 wv = sW1v[j * 4 + d4];
            s = fmaf(wv.x, h[4*d4+0], s); s = fmaf(wv.y, h[4*d4+1], s);
            s = fmaf(wv.z, h[4*d4+2], s); s = fmaf(wv.w, h[4*d4+3], s);
        }
        a1[jj] = silu_f(s);
    }

    float t0[16];
#pragma unroll
    for (int i = 0; i < 8; ++i) {
        const float mine  = a1[i];
        const float other = __shfl_xor(mine, 1);
        const bool hi = (q & 1);
        t0[i]     = hi ? other : mine;
        t0[8 + i] = hi ? mine  : other;
    }
    float A1[32];
#pragma unroll
    for (int i = 0; i < 16; ++i) {
        const float mine  = t0[i];
        const float other = __shfl_xor(mine, 2);
        const bool hi = (q & 2);
        A1[i]      = hi ? other : mine;
        A1[16 + i] = hi ? mine  : other;
    }

    const float4* __restrict__ sW2v = (const float4*)sW2;
    float part = 0.f;
#pragma unroll
    for (int jj = 0; jj < 8; ++jj) {
        const int j = 8 * q + jj;
        float s = sb2[j];
#pragma unroll
        for (int d4 = 0; d4 < 8; ++d4) {
            const float4 wv = sW2v[j * 8 + d4];
            s = fmaf(wv.x, A1[4*d4+0], s); s = fmaf(wv.y, A1[4*d4+1], s);
            s = fmaf(wv.z, A1[4*d4+2], s); s = fmaf(wv.w, A1[4*d4+3], s);
        }
        part = fmaf(sW3[j], silu_f(s), part);
    }
    part += __shfl_xor(part, 1);
    part += __shfl_xor(part, 2);
    if (q == 0) out[node] = part + sb3;
}

extern "C" void kernel_launch(void* const* d_in, const int* in_sizes, int n_in,
                              void* d_out, int out_size, void* d_ws, size_t ws_size,
                              hipStream_t stream)
{
    const float* x   = (const float*)d_in[0];
    const int*   ei  = (const int*)d_in[1];
    const float* Wl0 = (const float*)d_in[2];
    const float* bl0 = (const float*)d_in[3];
    const float* Wr0 = (const float*)d_in[4];
    const float* Wls = (const float*)d_in[5];
    const float* bls = (const float*)d_in[6];
    const float* Wrs = (const float*)d_in[7];
    const float* W1  = (const float*)d_in[8];
    const float* b1  = (const float*)d_in[9];
    const float* W2  = (const float*)d_in[10];
    const float* b2  = (const float*)d_in[11];
    const float* W3  = (const float*)d_in[12];
    const float* b3  = (const float*)d_in[13];

    const int n  = in_sizes[0] / 32;
    const int ne = in_sizes[1] / 2;
    const int* src = ei;
    const int* dst = ei + ne;
    const int nbuck   = (n + BWID - 1) >> SH;
    const int nblocks = (ne + CHUNK - 1) / CHUNK;
    const int G = (nblocks > nbuck) ? nblocks : nbuck;

    // workspace (shared by both paths)
    float*    acc0    = (float*)d_ws;
    float*    acc1    = acc0 + (size_t)n * 16;
    unsigned* hlbA    = (unsigned*)(acc1 + (size_t)n * 16);
    unsigned* hlbB    = hlbA + (size_t)n * 8;
    int2*     noff2   = (int2*)(hlbB + (size_t)n * 8);
    int*      binned1 = (int*)(noff2 + n);
    unsigned short* cnt16  = (unsigned short*)(binned1 + (size_t)nbuck * BCAP);
    unsigned short* scan16 = cnt16 + (size_t)nblocks * NBK;
    unsigned* binned0 = (unsigned*)(scan16 + (size_t)nblocks * NBK);

    // ---- try cooperative mega-kernel ----
    const void* src_p = src; const void* dst_p = dst; const void* x_p = x;
    const void* Wl0_p = Wl0; const void* bl0_p = bl0; const void* Wr0_p = Wr0;
    const void* Wls_p = Wls; const void* bls_p = bls; const void* Wrs_p = Wrs;
    const void* W1_p = W1; const void* b1_p = b1; const void* W2_p = W2;
    const void* b2_p = b2; const void* W3_p = W3; const void* b3_p = b3;
    void* out_p = d_out;
    int n_ = n, ne_ = ne, nblocks_ = nblocks, nbuck_ = nbuck;

    void* args[] = {
        (void*)&src_p, (void*)&dst_p, (void*)&x_p,
        (void*)&Wl0_p, (void*)&bl0_p, (void*)&Wr0_p,
        (void*)&Wls_p, (void*)&bls_p, (void*)&Wrs_p,
        (void*)&W1_p, (void*)&b1_p, (void*)&W2_p, (void*)&b2_p,
        (void*)&W3_p, (void*)&b3_p,
        (void*)&out_p,
        (void*)&cnt16, (void*)&scan16,
        (void*)&binned0, (void*)&binned1,
        (void*)&hlbA, (void*)&hlbB,
        (void*)&acc0, (void*)&acc1,
        (void*)&n_, (void*)&ne_, (void*)&nblocks_, (void*)&nbuck_
    };
    hipError_t err = hipLaunchCooperativeKernel(
        (const void*)mega, dim3(G), dim3(512), args, 0, stream);
    if (err == hipSuccess) return;

    // ---- fallback: proven R19 5-kernel path ----
    bin_dense0<<<nblocks, 256, 0, stream>>>(src, dst, cnt16, scan16, binned0,
                                            x, Wl0, bl0, Wr0, hlbA, acc0,
                                            n, ne, nblocks);
    sort_agg_dense<<<nbuck, 512, 0, stream>>>(binned0, cnt16, scan16,
        binned1, noff2, hlbA, acc0,
        Wls + 0, bls + 0, Wrs + 0, hlbB, acc1, n, nblocks);
    fused_agg_dense<<<(n * 4 + 255) / 256, 256, 0, stream>>>(noff2, binned1, hlbB, acc1,
        Wls + 256, bls + 16, Wrs + 256, hlbA, acc0, n);
    fused_agg_dense<<<(n * 4 + 255) / 256, 256, 0, stream>>>(noff2, binned1, hlbA, acc0,
        Wls + 512, bls + 32, Wrs + 512, hlbB, acc1, n);
    fused_agg_mlp<<<(n * 4 + 255) / 256, 256, 0, stream>>>(noff2, binned1, hlbB, acc1,
        W1, b1, W2, b2, W3, b3, (float*)d_out, n);
}

// Round 22
// 150.362 us; speedup vs baseline: 4.5038x; 4.5038x over previous
//
#include <hip/hip_runtime.h>

// GraphSAGE 4×SAGEConv + MLP head, fp32 in/out.
// R22 == R19 (best passing config, 150.5us). The cooperative mega-kernel
// experiment (R21: 645us) proved grid.sync phase-serialization is far worse
// than 5 dispatches with inter-kernel overlap. Pipeline:
//   bin_dense0: LDS-sort edge chunks by 256-node bucket + layer-0 dense
//   sort_agg_dense: per-bucket counting sort -> binned1 + noff2, then
//                   layer-1 agg+dense with LDS-resident CSR (L2-hot binned1)
//   fused_agg_dense x2 + fused_agg_mlp: gather + dense/MLP per layer.
// Key invariants learned: no float atomics, no 4B scattered global writes,
// bf16 messages (L2-resident), linear-before-scatter, wave shfl scans.

#define SH      8
#define BWID    256           // nodes per bucket
#define NBK     512           // cnt16/scan16 stride (pow2 >= nbuck=391)
#define CHUNK   4096
#define EPT     (CHUNK / 256)
#define BCAP    5120          // binned1 slots per bucket (load 4096+-64, +16s)

__device__ __forceinline__ float silu_f(float v) {
    return v * __builtin_amdgcn_rcpf(1.0f + __expf(-v));
}

__device__ __forceinline__ float bf_lo(unsigned u) { return __uint_as_float(u << 16); }
__device__ __forceinline__ float bf_hi(unsigned u) { return __uint_as_float(u & 0xFFFF0000u); }
__device__ __forceinline__ unsigned short f2bf(float f) {   // RNE
    unsigned x = __float_as_uint(f);
    unsigned r = x + 0x7FFFu + ((x >> 16) & 1u);
    return (unsigned short)(r >> 16);
}
__device__ __forceinline__ unsigned pack_bf2(float a, float b) {
    return (unsigned)f2bf(a) | ((unsigned)f2bf(b) << 16);
}

__device__ __forceinline__ int wave_iscan(int v, int lane) {
#pragma unroll
    for (int d = 1; d < 64; d <<= 1) {
        const int tv = __shfl_up(v, d);
        if (lane >= d) v += tv;
    }
    return v;
}

#define ACC2(u0, u1) \
    p[0] += bf_lo(u0.x); p[1] += bf_hi(u0.x); p[2] += bf_lo(u0.y); p[3] += bf_hi(u0.y); \
    p[4] += bf_lo(u0.z); p[5] += bf_hi(u0.z); p[6] += bf_lo(u0.w); p[7] += bf_hi(u0.w); \
    p[8] += bf_lo(u1.x); p[9] += bf_hi(u1.x); p[10]+= bf_lo(u1.y); p[11]+= bf_hi(u1.y); \
    p[12]+= bf_lo(u1.z); p[13]+= bf_hi(u1.z); p[14]+= bf_lo(u1.w); p[15]+= bf_hi(u1.w);

// ---------------- build ----------------

// LDS-sort chunk by bucket (512 bins), dense coalesced flush + publish
// (cnt,scan) u16; dense0 tail. 5 block barriers total.
__global__ __launch_bounds__(256) void bin_dense0(
    const int* __restrict__ src, const int* __restrict__ dst,
    unsigned short* __restrict__ cnt16,   // [nblocks*NBK]
    unsigned short* __restrict__ scan16,  // [nblocks*NBK]
    unsigned* __restrict__ binned0,       // [nblocks*CHUNK], dense per block
    const float* __restrict__ x,
    const float* __restrict__ Wl0, const float* __restrict__ bl0,
    const float* __restrict__ Wr0,
    unsigned* __restrict__ hlb, float* __restrict__ acc,
    int n, int ne, int nblocks)
{
    __shared__ int      s_hist[NBK];
    __shared__ int      s_off[NBK];
    __shared__ int      s_ws[4];
    __shared__ unsigned s_items[CHUNK];   // 16KB
    __shared__ float    sWl[512], sWr[512], sbl[16];

    const int t = threadIdx.x;
    const int lane = t & 63, w = t >> 6;
    const int blk = blockIdx.x;
    for (int i = t; i < 512; i += 256) { sWl[i] = Wl0[i]; sWr[i] = Wr0[i]; }
    if (t < 16) sbl[t] = bl0[t];

    const int base = blk * CHUNK;
    const int cnt = min(CHUNK, ne - base);

    int es[EPT], ed[EPT];
#pragma unroll
    for (int j = 0; j < EPT; ++j) {
        const int i = t + j * 256;
        if (i < cnt) {
            es[j] = __builtin_nontemporal_load(src + base + i);
            ed[j] = __builtin_nontemporal_load(dst + base + i);
        } else { es[j] = -1; ed[j] = -1; }
    }

    s_hist[t] = 0; s_hist[t + 256] = 0;
    __syncthreads();
#pragma unroll
    for (int j = 0; j < EPT; ++j)
        if (es[j] >= 0) atomicAdd(&s_hist[ed[j] >> SH], 1);
    __syncthreads();

    // 512-bin exclusive scan: pair-sums -> wave shfl scan (1 barrier)
    const int c0 = s_hist[2 * t], c1 = s_hist[2 * t + 1];
    const int ps = c0 + c1;
    const int inc = wave_iscan(ps, lane);
    if (lane == 63) s_ws[w] = inc;
    __syncthreads();
    int wbase = 0;
    for (int i = 0; i < w; ++i) wbase += s_ws[i];
    const int ex = inc + wbase - ps;
    s_off[2 * t] = ex;
    s_off[2 * t + 1] = ex + c0;

    // publish from registers (coalesced u16 pairs); reset cursors
    cnt16[blk * NBK + 2 * t]      = (unsigned short)c0;
    cnt16[blk * NBK + 2 * t + 1]  = (unsigned short)c1;
    scan16[blk * NBK + 2 * t]     = (unsigned short)ex;
    scan16[blk * NBK + 2 * t + 1] = (unsigned short)(ex + c0);
    s_hist[t] = 0; s_hist[t + 256] = 0;
    __syncthreads();

#pragma unroll
    for (int j = 0; j < EPT; ++j) {
        if (es[j] >= 0) {
            const int b  = ed[j] >> SH;
            const int ld = ed[j] & (BWID - 1);
            const int r  = atomicAdd(&s_hist[b], 1);
            s_items[s_off[b] + r] = ((unsigned)ld << 17) | (unsigned)es[j];
        }
    }
    __syncthreads();

    for (int i = t; i < cnt; i += 256)
        __builtin_nontemporal_store(s_items[i], binned0 + base + i);

    // ---- dense0 tail: 256 nodes/block ----
    const int node = blk * 256 + t;
    if (node >= n) return;

    float h[32];
    const float4* __restrict__ xp = (const float4*)(x + (size_t)node * 32);
#pragma unroll
    for (int r = 0; r < 8; ++r) {
        const float4 vv = xp[r];
        h[4*r+0] = vv.x; h[4*r+1] = vv.y; h[4*r+2] = vv.z; h[4*r+3] = vv.w;
    }

    const float4* __restrict__ sWl4 = (const float4*)sWl;
    const float4* __restrict__ sWr4 = (const float4*)sWr;
    float ol[16], oa[16];
#pragma unroll
    for (int j = 0; j < 16; ++j) {
        float al = 0.f, ar = 0.f;
#pragma unroll
        for (int d4 = 0; d4 < 8; ++d4) {
            const float4 wl = sWl4[j * 8 + d4];
            const float4 wr = sWr4[j * 8 + d4];
            al = fmaf(wl.x, h[4*d4+0], al); al = fmaf(wl.y, h[4*d4+1], al);
            al = fmaf(wl.z, h[4*d4+2], al); al = fmaf(wl.w, h[4*d4+3], al);
            ar = fmaf(wr.x, h[4*d4+0], ar); ar = fmaf(wr.y, h[4*d4+1], ar);
            ar = fmaf(wr.z, h[4*d4+2], ar); ar = fmaf(wr.w, h[4*d4+3], ar);
        }
        ol[j] = al;
        oa[j] = sbl[j] + ar;
    }

    unsigned u[8];
#pragma unroll
    for (int r = 0; r < 8; ++r) u[r] = pack_bf2(ol[2*r], ol[2*r+1]);
    uint4* __restrict__ hp = (uint4*)(hlb + (size_t)node * 8);
    hp[0] = make_uint4(u[0], u[1], u[2], u[3]);
    hp[1] = make_uint4(u[4], u[5], u[6], u[7]);
    float4* __restrict__ ap = (float4*)(acc + (size_t)node * 16);
#pragma unroll
    for (int r = 0; r < 4; ++r)
        ap[r] = make_float4(oa[4*r], oa[4*r+1], oa[4*r+2], oa[4*r+3]);
}

// ---------------- layers ----------------

// 2-lane gather (idx-quad), pair-combine via shfl_xor(1)
__device__ __forceinline__ void gather16_2(
    const int* __restrict__ binned1, const uint4* __restrict__ h4,
    int beg, int end, int q, float* p)
{
#pragma unroll
    for (int i = 0; i < 16; ++i) p[i] = 0.f;
    int base = beg;
    for (; base + 8 <= end; base += 8) {
        const int k = base + q * 4;
        const int i0 = binned1[k],     i1 = binned1[k + 1];
        const int i2 = binned1[k + 2], i3 = binned1[k + 3];
        const uint4 a0 = h4[(size_t)i0 * 2], a1 = h4[(size_t)i0 * 2 + 1];
        const uint4 b0 = h4[(size_t)i1 * 2], b1 = h4[(size_t)i1 * 2 + 1];
        const uint4 c0 = h4[(size_t)i2 * 2], c1 = h4[(size_t)i2 * 2 + 1];
        const uint4 d0 = h4[(size_t)i3 * 2], d1 = h4[(size_t)i3 * 2 + 1];
        ACC2(a0, a1)
        ACC2(b0, b1)
        ACC2(c0, c1)
        ACC2(d0, d1)
    }
    for (int k = base + q; k < end; k += 2) {
        const int s0 = binned1[k];
        const uint4 a0 = h4[(size_t)s0 * 2], a1 = h4[(size_t)s0 * 2 + 1];
        ACC2(a0, a1)
    }
#pragma unroll
    for (int i = 0; i < 16; ++i) p[i] += __shfl_xor(p[i], 1);
}

// 4-lane gather, idx-vectorized
__device__ __forceinline__ void gather16_4(
    const int* __restrict__ binned1, const uint4* __restrict__ h4,
    int beg, int end, int q, float* p)
{
#pragma unroll
    for (int i = 0; i < 16; ++i) p[i] = 0.f;
    int base = beg;
    for (; base + 16 <= end; base += 16) {
        const int k = base + q * 4;
        const int i0 = binned1[k],     i1 = binned1[k + 1];
        const int i2 = binned1[k + 2], i3 = binned1[k + 3];
        const uint4 a0 = h4[(size_t)i0 * 2], a1 = h4[(size_t)i0 * 2 + 1];
        const uint4 b0 = h4[(size_t)i1 * 2], b1 = h4[(size_t)i1 * 2 + 1];
        const uint4 c0 = h4[(size_t)i2 * 2], c1 = h4[(size_t)i2 * 2 + 1];
        const uint4 d0 = h4[(size_t)i3 * 2], d1 = h4[(size_t)i3 * 2 + 1];
        ACC2(a0, a1)
        ACC2(b0, b1)
        ACC2(c0, c1)
        ACC2(d0, d1)
    }
    for (int k = base + q; k < end; k += 4) {
        const int s0 = binned1[k];
        const uint4 a0 = h4[(size_t)s0 * 2], a1 = h4[(size_t)s0 * 2 + 1];
        ACC2(a0, a1)
    }
#pragma unroll
    for (int i = 0; i < 16; ++i) p[i] += __shfl_xor(p[i], 1);
#pragma unroll
    for (int i = 0; i < 16; ++i) p[i] += __shfl_xor(p[i], 2);
}

// FUSED: node_sort + layer-1 agg+dense. 512 thr = 256 nodes x 2 lanes.
// 6 block barriers total.
__global__ __launch_bounds__(512, 4) void sort_agg_dense(
    const unsigned* __restrict__ binned0,
    const unsigned short* __restrict__ cnt16,
    const unsigned short* __restrict__ scan16,
    int* __restrict__ binned1,            // [nbuck*BCAP]
    int2* __restrict__ noff2,             // [n] (for layers 2-4)
    const unsigned* __restrict__ hl_in,
    const float* __restrict__ acc_in,
    const float* __restrict__ Wl, const float* __restrict__ bl,
    const float* __restrict__ Wr,
    unsigned* __restrict__ hl_out, float* __restrict__ acc_out,
    int n, int nblocks)
{
    __shared__ unsigned s_edges[BCAP];    // 20KB staged bucket
    __shared__ int cnt[BWID];
    __shared__ int off_[BWID];
    __shared__ int s_ws[8];
    __shared__ int s_ws2[4];
    __shared__ float sWl[256], sWr[256], sbl[16];
    const int b = blockIdx.x, t = threadIdx.x;
    const int lane = t & 63, w = t >> 6;
    const int dbase = b * BCAP;

    if (t < 256) { sWl[t] = Wl[t]; sWr[t] = Wr[t]; }
    if (t < 16) sbl[t] = bl[t];

    // ---- staging-base scan: 1 run/thread, wave shfl scan (1 barrier) ----
    int rc = 0, rs = 0;
    if (t < nblocks) { rc = cnt16[t * NBK + b]; rs = scan16[t * NBK + b]; }
    const int inc = wave_iscan(rc, lane);
    if (lane == 63) s_ws[w] = inc;
    if (t < BWID) cnt[t] = 0;
    __syncthreads();                                   // B1
    int wbase = 0;
    for (int i = 0; i < w; ++i) wbase += s_ws[i];
    const int o = inc + wbase - rc;
    int tot = 0;
    for (int i = 0; i < 8; ++i) tot += s_ws[i];

    if (rc) {
        const unsigned* __restrict__ run = binned0 + (size_t)t * CHUNK + rs;
        for (int r = 0; r < rc; ++r)
            s_edges[o + r] = __builtin_nontemporal_load(run + r);
    }
    __syncthreads();                                   // B2

    for (int k = t; k < tot; k += 512)
        atomicAdd(&cnt[s_edges[k] >> 17], 1);
    __syncthreads();                                   // B3

    // 256-bin exclusive scan via wave shfl (first 4 waves carry data)
    const int c = (t < BWID) ? cnt[t] : 0;
    const int inc2 = wave_iscan(c, lane);
    if (lane == 63 && w < 4) s_ws2[w] = inc2;
    __syncthreads();                                   // B4
    if (t < BWID) {
        int wb2 = 0;
        for (int i = 0; i < w; ++i) wb2 += s_ws2[i];
        const int e = inc2 + wb2 - c;
        off_[t] = e;
        const int node = (b << SH) + t;
        if (node < n)
            noff2[node] = make_int2(dbase + e, dbase + e + c);
        cnt[t] = 0;
    }
    __syncthreads();                                   // B5

    for (int k = t; k < tot; k += 512) {
        const unsigned u = s_edges[k];
        const int ld = (int)(u >> 17);
        const int r2 = atomicAdd(&cnt[ld], 1);
        binned1[dbase + off_[ld] + r2] = (int)(u & 0x1FFFFu);
    }
    __syncthreads();                                   // B6

    // ---- layer-1 agg+dense: 256 nodes x 2 lanes; binned1 L2-hot ----
    const int ln = t >> 1;
    const int node = (b << SH) + ln;
    if (node >= n) return;
    const int q = t & 1;
    const int beg = dbase + off_[ln];
    const int end = beg + cnt[ln];

    float p[16];
    gather16_2(binned1, (const uint4*)hl_in, beg, end, q, p);

    const float4* __restrict__ ai = (const float4*)(acc_in + (size_t)node * 16);
    float h[16];
#pragma unroll
    for (int r = 0; r < 4; ++r) {
        const float4 a = ai[r];
        h[4*r+0] = silu_f(a.x + p[4*r+0]);
        h[4*r+1] = silu_f(a.y + p[4*r+1]);
        h[4*r+2] = silu_f(a.z + p[4*r+2]);
        h[4*r+3] = silu_f(a.w + p[4*r+3]);
    }

    const float4* __restrict__ sWl4 = (const float4*)sWl;
    const float4* __restrict__ sWr4 = (const float4*)sWr;
    float ol[8], oa[8];
#pragma unroll
    for (int jj = 0; jj < 8; ++jj) {
        const int j = 8 * q + jj;
        float al = 0.f, ar = 0.f;
#pragma unroll
        for (int d4 = 0; d4 < 4; ++d4) {
            const float4 wl = sWl4[j * 4 + d4];
            const float4 wr = sWr4[j * 4 + d4];
            al = fmaf(wl.x, h[4*d4+0], al); al = fmaf(wl.y, h[4*d4+1], al);
            al = fmaf(wl.z, h[4*d4+2], al); al = fmaf(wl.w, h[4*d4+3], al);
            ar = fmaf(wr.x, h[4*d4+0], ar); ar = fmaf(wr.y, h[4*d4+1], ar);
            ar = fmaf(wr.z, h[4*d4+2], ar); ar = fmaf(wr.w, h[4*d4+3], ar);
        }
        ol[jj] = al;
        oa[jj] = sbl[j] + ar;
    }

    ((uint4*)hl_out)[(size_t)node * 2 + q] =
        make_uint4(pack_bf2(ol[0], ol[1]), pack_bf2(ol[2], ol[3]),
                   pack_bf2(ol[4], ol[5]), pack_bf2(ol[6], ol[7]));
    float4* __restrict__ ap = (float4*)(acc_out + (size_t)node * 16);
    ap[2 * q]     = make_float4(oa[0], oa[1], oa[2], oa[3]);
    ap[2 * q + 1] = make_float4(oa[4], oa[5], oa[6], oa[7]);
}

// agg(layer i) + dense(layer i+1): 4 lanes/node, 64 nodes/block
__global__ __launch_bounds__(256, 4) void fused_agg_dense(
    const int2* __restrict__ noff2, const int* __restrict__ binned1,
    const unsigned* __restrict__ hl_in, const float* __restrict__ acc_in,
    const float* __restrict__ Wl, const float* __restrict__ bl,
    const float* __restrict__ Wr,
    unsigned* __restrict__ hl_out, float* __restrict__ acc_out, int n)
{
    __shared__ float sWl[256], sWr[256], sbl[16];
    const int t = threadIdx.x;
    sWl[t] = Wl[t]; sWr[t] = Wr[t];
    if (t < 16) sbl[t] = bl[t];
    __syncthreads();

    const int gid = blockIdx.x * 256 + t;
    const int node = gid >> 2;
    if (node >= n) return;
    const int q = t & 3;
    const int2 be = noff2[node];

    float p[16];
    gather16_4(binned1, (const uint4*)hl_in, be.x, be.y, q, p);

    const float4* __restrict__ ai = (const float4*)(acc_in + (size_t)node * 16);
    float h[16];
#pragma unroll
    for (int r = 0; r < 4; ++r) {
        const float4 a = ai[r];
        h[4*r+0] = silu_f(a.x + p[4*r+0]);
        h[4*r+1] = silu_f(a.y + p[4*r+1]);
        h[4*r+2] = silu_f(a.z + p[4*r+2]);
        h[4*r+3] = silu_f(a.w + p[4*r+3]);
    }

    const float4* __restrict__ sWl4 = (const float4*)sWl;
    const float4* __restrict__ sWr4 = (const float4*)sWr;
    float ol[4], oa[4];
#pragma unroll
    for (int jj = 0; jj < 4; ++jj) {
        const int j = 4 * q + jj;
        float al = 0.f, ar = 0.f;
#pragma unroll
        for (int d4 = 0; d4 < 4; ++d4) {
            const float4 wl = sWl4[j * 4 + d4];
            const float4 wr = sWr4[j * 4 + d4];
            al = fmaf(wl.x, h[4*d4+0], al); al = fmaf(wl.y, h[4*d4+1], al);
            al = fmaf(wl.z, h[4*d4+2], al); al = fmaf(wl.w, h[4*d4+3], al);
            ar = fmaf(wr.x, h[4*d4+0], ar); ar = fmaf(wr.y, h[4*d4+1], ar);
            ar = fmaf(wr.z, h[4*d4+2], ar); ar = fmaf(wr.w, h[4*d4+3], ar);
        }
        ol[jj] = al;
        oa[jj] = sbl[j] + ar;
    }

    ((uint2*)hl_out)[(size_t)node * 4 + q] =
        make_uint2(pack_bf2(ol[0], ol[1]), pack_bf2(ol[2], ol[3]));
    ((float4*)acc_out)[(size_t)node * 4 + q] =
        make_float4(oa[0], oa[1], oa[2], oa[3]);
}

// agg(layer 3) + MLP head: 4 lanes/node
__global__ __launch_bounds__(256, 3) void fused_agg_mlp(
    const int2* __restrict__ noff2, const int* __restrict__ binned1,
    const unsigned* __restrict__ hl_in, const float* __restrict__ acc_in,
    const float* __restrict__ W1, const float* __restrict__ b1,
    const float* __restrict__ W2, const float* __restrict__ b2,
    const float* __restrict__ W3, const float* __restrict__ b3,
    float* __restrict__ out, int n)
{
    __shared__ float sW1[512], sW2[1024], sb1[32], sb2[32], sW3[32];
    __shared__ float sb3;
    const int t = threadIdx.x;
    for (int i = t; i < 512; i += 256) sW1[i] = W1[i];
    for (int i = t; i < 1024; i += 256) sW2[i] = W2[i];
    if (t < 32) { sb1[t] = b1[t]; sb2[t] = b2[t]; sW3[t] = W3[t]; }
    if (t == 0) sb3 = b3[0];
    __syncthreads();

    const int gid = blockIdx.x * 256 + t;
    const int node = gid >> 2;
    if (node >= n) return;
    const int q = t & 3;
    const int2 be = noff2[node];

    float p[16];
    gather16_4(binned1, (const uint4*)hl_in, be.x, be.y, q, p);

    const float4* __restrict__ ai = (const float4*)(acc_in + (size_t)node * 16);
    float h[16];
#pragma unroll
    for (int r = 0; r < 4; ++r) {
        const float4 a = ai[r];
        h[4*r+0] = silu_f(a.x + p[4*r+0]);
        h[4*r+1] = silu_f(a.y + p[4*r+1]);
        h[4*r+2] = silu_f(a.z + p[4*r+2]);
        h[4*r+3] = silu_f(a.w + p[4*r+3]);
    }

    const float4* __restrict__ sW1v = (const float4*)sW1;
    float a1[8];
#pragma unroll
    for (int jj = 0; jj < 8; ++jj) {
        const int j = 8 * q + jj;
        float s = sb1[j];
#pragma unroll
        for (int d4 = 0; d4 < 4; ++d4) {
            const float4 wv = sW1v[j * 4 + d4];
            s = fmaf(wv.x, h[4*d4+0], s); s = fmaf(wv.y, h[4*d4+1], s);
            s = fmaf(wv.z, h[4*d4+2], s); s = fmaf(wv.w, h[4*d4+3], s);
        }
        a1[jj] = silu_f(s);
    }

    float t0[16];
#pragma unroll
    for (int i = 0; i < 8; ++i) {
        const float mine  = a1[i];
        const float other = __shfl_xor(mine, 1);
        const bool hi = (q & 1);
        t0[i]     = hi ? other : mine;
        t0[8 + i] = hi ? mine  : other;
    }
    float A1[32];
#pragma unroll
    for (int i = 0; i < 16; ++i) {
        const float mine  = t0[i];
        const float other = __shfl_xor(mine, 2);
        const bool hi = (q & 2);
        A1[i]      = hi ? other : mine;
        A1[16 + i] = hi ? mine  : other;
    }

    const float4* __restrict__ sW2v = (const float4*)sW2;
    float part = 0.f;
#pragma unroll
    for (int jj = 0; jj < 8; ++jj) {
        const int j = 8 * q + jj;
        float s = sb2[j];
#pragma unroll
        for (int d4 = 0; d4 < 8; ++d4) {
            const float4 wv = sW2v[j * 8 + d4];
            s = fmaf(wv.x, A1[4*d4+0], s); s = fmaf(wv.y, A1[4*d4+1], s);
            s = fmaf(wv.z, A1[4*d4+2], s); s = fmaf(wv.w, A1[4*d4+3], s);
        }
        part = fmaf(sW3[j], silu_f(s), part);
    }
    part += __shfl_xor(part, 1);
    part += __shfl_xor(part, 2);
    if (q == 0) out[node] = part + sb3;
}

extern "C" void kernel_launch(void* const* d_in, const int* in_sizes, int n_in,
                              void* d_out, int out_size, void* d_ws, size_t ws_size,
                              hipStream_t stream)
{
    const float* x   = (const float*)d_in[0];
    const int*   ei  = (const int*)d_in[1];
    const float* Wl0 = (const float*)d_in[2];
    const float* bl0 = (const float*)d_in[3];
    const float* Wr0 = (const float*)d_in[4];
    const float* Wls = (const float*)d_in[5];
    const float* bls = (const float*)d_in[6];
    const float* Wrs = (const float*)d_in[7];
    const float* W1  = (const float*)d_in[8];
    const float* b1  = (const float*)d_in[9];
    const float* W2  = (const float*)d_in[10];
    const float* b2  = (const float*)d_in[11];
    const float* W3  = (const float*)d_in[12];
    const float* b3  = (const float*)d_in[13];

    const int n  = in_sizes[0] / 32;
    const int ne = in_sizes[1] / 2;
    const int* src = ei;
    const int* dst = ei + ne;
    const int nbuck   = (n + BWID - 1) >> SH;
    const int nblocks = (ne + CHUNK - 1) / CHUNK;

    // workspace (~42 MB; ws is ~268 MB per harness fill size)
    float*    acc0    = (float*)d_ws;                        // [n*16]
    float*    acc1    = acc0 + (size_t)n * 16;               // [n*16]
    unsigned* hlbA    = (unsigned*)(acc1 + (size_t)n * 16);  // [n*8]
    unsigned* hlbB    = hlbA + (size_t)n * 8;                // [n*8]
    int2*     noff2   = (int2*)(hlbB + (size_t)n * 8);       // [n]
    int*      binned1 = (int*)(noff2 + n);                   // [nbuck*BCAP]
    unsigned short* cnt16  = (unsigned short*)(binned1 + (size_t)nbuck * BCAP); // [nblocks*NBK]
    unsigned short* scan16 = cnt16 + (size_t)nblocks * NBK;                     // [nblocks*NBK]
    unsigned* binned0 = (unsigned*)(scan16 + (size_t)nblocks * NBK);  // [nblocks*CHUNK]

    const int lb = (n * 4 + 255) / 256;   // layer blocks: 4 lanes/node

    // ---- build + layer 1 (fused) ----
    bin_dense0<<<nblocks, 256, 0, stream>>>(src, dst, cnt16, scan16, binned0,
                                            x, Wl0, bl0, Wr0, hlbA, acc0,
                                            n, ne, nblocks);
    sort_agg_dense<<<nbuck, 512, 0, stream>>>(binned0, cnt16, scan16,
        binned1, noff2, hlbA, acc0,
        Wls + 0, bls + 0, Wrs + 0, hlbB, acc1, n, nblocks);

    // ---- layers 2-4 ----
    fused_agg_dense<<<lb, 256, 0, stream>>>(noff2, binned1, hlbB, acc1,
        Wls + 256, bls + 16, Wrs + 256, hlbA, acc0, n);
    fused_agg_dense<<<lb, 256, 0, stream>>>(noff2, binned1, hlbA, acc0,
        Wls + 512, bls + 32, Wrs + 512, hlbB, acc1, n);
    fused_agg_mlp<<<lb, 256, 0, stream>>>(noff2, binned1, hlbB, acc1,
        W1, b1, W2, b2, W3, b3, (float*)d_out, n);
}